// Round 6
// baseline (63.135 us; speedup 1.0000x reference)
//
#include <hip/hip_runtime.h>
#include <math.h>

// Problem constants (match reference)
constexpr int B = 4, S = 128, D = 256, TC = 1024;  // TC = D*4 (d,c flattened)
constexpr float EPS = 1e-6f;
constexpr int KS = 16, KW = 64;      // split-K for G (KS*KW = TC)
constexpr int ROWS = 8, TCOLS = 256; // consumer tiling
constexpr int NBLK = 256;

// ws layout (floats): Wv[S][TC] | SWq[S*4] | SWk[S*4] | Gpart[KS][S][S] | counter
constexpr size_t WV_N = (size_t)S * TC;          // 131072
constexpr size_t GP_OFF = WV_N + 512 + 512;      // 132096
constexpr size_t CNT_OFF = GP_OFF + (size_t)KS * S * S;  // 394240

// ---------------------------------------------------------------------------
// Single kernel, 256 blocks. Phase P (producer): block p computes
//   Gpart[ks][i0..i0+7][0..127] for (it=p>>4, ks=p&15), Wq/Wk exp'd inline
//   (exact R5 kA math);  blocks p<128 additionally write Wv row p and
//   SWq/SWk row p (exact R5 role-2 math).
// Release: __threadfence + agent atomic inc. All blocks then acquire-poll to
// NBLK (bounded), fence (invalidates this XCD's L2 -> no stale replay data),
// and run the R5 kB body for (tt=p&3, yt=(p>>2)&15, b=p>>6).
// LDS: 10816 floats (43.3 KB) -> >=3 blocks/CU capacity: 256 blocks always
// co-resident on an idle 256-CU device; no dispatch-order assumption needed
// beyond eager placement.
// ---------------------------------------------------------------------------
__global__ __launch_bounds__(256)
void qlns_one(const float* __restrict__ query, const float* __restrict__ key_in,
              const float* __restrict__ value,
              const float* __restrict__ qw, const float* __restrict__ qb,
              const float* __restrict__ kw, const float* __restrict__ kb,
              const float* __restrict__ vw, const float* __restrict__ vb,
              float* __restrict__ Wv, float* __restrict__ SWq,
              float* __restrict__ SWk, float* __restrict__ Gpart,
              unsigned int* __restrict__ cnt, float* __restrict__ out)
{
    __shared__ __align__(16) float sh[10816];
    const int p = blockIdx.x, tid = threadIdx.x;

    // ---------------- producer: G slice ----------------
    {
        float* wkT = sh;            // [KW][S+1]  64x129
        float* wqs = sh + 8256;     // [8][KW+4]  8x68 (16B-aligned rows)
        float* ekb = sh + 8800;     // [64]
        float* eqb = sh + 8864;     // [64]
        const int it = p >> 4, ks = p & 15;
        const int k0 = ks * KW, d0 = k0 >> 2, i0 = it * 8;

        if (tid < KW) {
            ekb[tid] = __expf(kb[k0 + tid]);
            eqb[tid] = __expf(qb[k0 + tid]);
        }
        __syncthreads();

        for (int e = tid; e < 4 * S * 16; e += 256) {   // K slice [4c][128j][16dd]
            int c = e >> 11, j = (e >> 4) & 127, dd = e & 15;
            int kk = dd * 4 + c;
            wkT[kk * (S + 1) + j] = __expf(kw[(c * S + j) * D + d0 + dd]) + ekb[kk];
        }
        for (int e = tid; e < 4 * 8 * 16; e += 256) {   // Q tile [4c][8i][16dd]
            int c = e >> 7, i = (e >> 4) & 7, dd = e & 15;
            int kk = dd * 4 + c;
            wqs[i * (KW + 4) + kk] = __expf(qw[(c * S + i0 + i) * D + d0 + dd]) + eqb[kk];
        }
        __syncthreads();

        const int j = tid & 127, ih = tid >> 7;   // 2 i-halves of 4 rows
        float acc[4] = {0.f, 0.f, 0.f, 0.f};
        for (int k = 0; k < KW; k += 4) {
            float kv0 = wkT[k * (S + 1) + j],       kv1 = wkT[(k + 1) * (S + 1) + j];
            float kv2 = wkT[(k + 2) * (S + 1) + j], kv3 = wkT[(k + 3) * (S + 1) + j];
            #pragma unroll
            for (int r = 0; r < 4; ++r) {
                float4 q = *(const float4*)&wqs[(ih * 4 + r) * (KW + 4) + k];
                acc[r] += q.x * kv0 + q.y * kv1 + q.z * kv2 + q.w * kv3;
            }
        }
        #pragma unroll
        for (int r = 0; r < 4; ++r)
            Gpart[(ks * S + i0 + ih * 4 + r) * S + j] = acc[r];
    }

    // ---------------- producer: Wv / SWq / SWk rows (blocks 0..127) -----------
    if (p < S) {
        float* redq = sh + 8928;    // [256]
        float* redk = sh + 9184;    // [256]
        const int s = p;
        float pq = 0.f, pk = 0.f;
        #pragma unroll
        for (int r = 0; r < 4; ++r) {
            int t = r * 256 + tid;
            int c = t & 3, d = t >> 2;
            int wi = (c * S + s) * D + d;            // [4,S,D]
            pq += __expf(qw[wi]) + __expf(qb[t]);
            pk += __expf(kw[wi]) + __expf(kb[t]);
            Wv[s * TC + t] = __expf(vw[wi]) + __expf(vb[t]);
        }
        redq[tid] = pq; redk[tid] = pk;
        __syncthreads();
        if (tid < 4) {
            float sq = 0.f, sk = 0.f;
            for (int u = tid; u < 256; u += 4) { sq += redq[u]; sk += redk[u]; }
            SWq[s * 4 + tid] = sq; SWk[s * 4 + tid] = sk;
        }
    }

    // ---------------- release / acquire sync ----------------
    __syncthreads();
    if (tid == 0) {
        __threadfence();   // device-scope release: wb this XCD's L2
        __hip_atomic_fetch_add(cnt, 1u, __ATOMIC_RELEASE, __HIP_MEMORY_SCOPE_AGENT);
        unsigned int guard = 0;
        while (__hip_atomic_load(cnt, __ATOMIC_ACQUIRE, __HIP_MEMORY_SCOPE_AGENT)
                   < (unsigned int)NBLK && guard < (1u << 20)) {
            __builtin_amdgcn_s_sleep(8);
            ++guard;
        }
        __threadfence();   // device-scope acquire: invalidate L1 + this XCD's L2
    }
    __syncthreads();

    // ---------------- consumer: scores + softmax + PV (R5 kB) ----------------
    {
        float* wvS  = sh;           // [32][256] staging round
        float* att  = sh + 8192;    // [8][128]
        float* xkl  = sh + 9216;    // [128][4]
        float* xvl  = sh + 9728;
        float* swkl = sh + 10240;
        float* xql  = sh + 10752;   // [8][4]
        float* swql = sh + 10784;
        const int tt = p & 3, yt = (p >> 2) & 15, b = p >> 6;
        const int i0 = yt * ROWS;

        for (int e = tid; e < S * 4; e += 256) {
            xkl[e]  = fmaxf(key_in[b * S * 4 + e], EPS);
            xvl[e]  = fmaxf(value[b * S * 4 + e], EPS);
            swkl[e] = SWk[e];
        }
        if (tid < ROWS * 4) {
            xql[tid]  = fmaxf(query[(b * S + i0) * 4 + tid], EPS);
            swql[tid] = SWq[i0 * 4 + tid];
        }
        __syncthreads();

        for (int e = tid; e < ROWS * S; e += 256) {
            int i = e >> 7, j = e & 127;
            float g = 0.f;
            #pragma unroll
            for (int ks2 = 0; ks2 < KS; ++ks2)
                g += Gpart[(ks2 * S + i0 + i) * S + j];
            float sc = g;
            #pragma unroll
            for (int c = 0; c < 4; ++c)
                sc += (float)D * xql[i * 4 + c] * xkl[j * 4 + c]
                    + xql[i * 4 + c] * swkl[j * 4 + c]
                    + swql[i * 4 + c] * xkl[j * 4 + c];
            att[i * S + j] = sc;
        }
        __syncthreads();

        {
            const int w = tid >> 6, lane = tid & 63;
            #pragma unroll
            for (int rr = 0; rr < ROWS / 4; ++rr) {
                int i = w + rr * 4;
                float s0 = att[i * S + lane], s1 = att[i * S + lane + 64];
                float m = fmaxf(s0, s1);
                #pragma unroll
                for (int o = 32; o > 0; o >>= 1) m = fmaxf(m, __shfl_xor(m, o));
                float e0 = __expf(s0 - m), e1 = __expf(s1 - m);
                float sum = e0 + e1;
                #pragma unroll
                for (int o = 32; o > 0; o >>= 1) sum += __shfl_xor(sum, o);
                float inv = 1.f / sum;
                att[i * S + lane]      = fmaxf(e0 * inv, EPS);  // _to_log clamp
                att[i * S + lane + 64] = fmaxf(e1 * inv, EPS);
            }
        }
        __syncthreads();

        float acc[ROWS];
        #pragma unroll
        for (int i = 0; i < ROWS; ++i) acc[i] = 0.f;

        for (int h = 0; h < 4; ++h) {       // 4 rounds x 32 j-rows (ascending j)
            for (int e = tid; e < 32 * 64; e += 256) {
                int jr = e >> 6, c4 = (e & 63) * 4;
                float4 wv = *(const float4*)&Wv[(size_t)(h * 32 + jr) * TC + tt * TCOLS + c4];
                float4 xv = *(const float4*)&xvl[(h * 32 + jr) * 4];
                float4 o;
                o.x = wv.x + xv.x; o.y = wv.y + xv.y;
                o.z = wv.z + xv.z; o.w = wv.w + xv.w;
                *(float4*)&wvS[jr * TCOLS + c4] = o;
            }
            __syncthreads();
            for (int jj = 0; jj < 32; jj += 4) {
                float v0 = wvS[jj * TCOLS + tid],       v1 = wvS[(jj + 1) * TCOLS + tid];
                float v2 = wvS[(jj + 2) * TCOLS + tid], v3 = wvS[(jj + 3) * TCOLS + tid];
                int jb = h * 32 + jj;
                #pragma unroll
                for (int i = 0; i < ROWS; ++i) {
                    float4 a = *(const float4*)&att[i * S + jb];
                    acc[i] += a.x * v0 + a.y * v1 + a.z * v2 + a.w * v3;
                }
            }
            __syncthreads();
        }

        float* ob = out + (size_t)(b * S + i0) * TC + tt * TCOLS + tid;
        #pragma unroll
        for (int i = 0; i < ROWS; ++i) ob[i * TC] = acc[i];
    }
}

extern "C" void kernel_launch(void* const* d_in, const int* in_sizes, int n_in,
                              void* d_out, int out_size, void* d_ws, size_t ws_size,
                              hipStream_t stream)
{
    const float* query  = (const float*)d_in[0];
    const float* key_in = (const float*)d_in[1];
    const float* value  = (const float*)d_in[2];
    const float* qw = (const float*)d_in[3];
    const float* qb = (const float*)d_in[4];
    const float* kw = (const float*)d_in[5];
    const float* kb = (const float*)d_in[6];
    const float* vw = (const float*)d_in[7];
    const float* vb = (const float*)d_in[8];
    float* out = (float*)d_out;

    float* Wv    = (float*)d_ws;
    float* SWq   = Wv + WV_N;
    float* SWk   = SWq + S * 4;
    float* Gpart = (float*)d_ws + GP_OFF;
    unsigned int* cnt = (unsigned int*)((float*)d_ws + CNT_OFF);

    hipMemsetAsync(cnt, 0, sizeof(unsigned int), stream);
    qlns_one<<<NBLK, 256, 0, stream>>>(query, key_in, value,
                                       qw, qb, kw, kb, vw, vb,
                                       Wv, SWq, SWk, Gpart, cnt, out);
}